// Round 2
// baseline (756.850 us; speedup 1.0000x reference)
//
#include <hip/hip_runtime.h>

typedef __bf16 bf16;
typedef __attribute__((ext_vector_type(4))) __bf16 bf16x4;
typedef __attribute__((ext_vector_type(8))) __bf16 bf16x8;
typedef __attribute__((ext_vector_type(4))) float f32x4;

#define DEVINL __device__ __forceinline__

typedef __attribute__((address_space(1))) void gvoid_t;
typedef __attribute__((address_space(3))) void lvoid_t;

DEVINL void async_ld16(const void* g, void* l) {
    __builtin_amdgcn_global_load_lds((gvoid_t*)g, (lvoid_t*)l, 16, 0, 0);
}

// Device-coherent (cross-XCD safe) f32 atomic add: native global_atomic_add_f32
// with sc1 -> performed at the device coherence point, not the local XCD L2.
DEVINL void atomic_add_f32_dev(float* p, float v) {
    asm volatile("global_atomic_add_f32 %0, %1, off sc1"
                 :: "v"(p), "v"(v) : "memory");
}

// C(M x N) = relu(A(M x K) @ Bt^T + bias); A,Bt bf16; bias f32.
// 128x128 tile, BK=64, 256 threads = 4 waves (2x2 of 64x64), 16x16x32 bf16 MFMA.
// Swapped operands: mfma(bfr, af) -> row(M)=lane&15 in lanes, 4 consecutive
// cols(N) in regs -> vectorized stores.
// 1-D grid + XCD swizzle: id&7 = XCD (round-robin dispatch), all NBN blocks of
// one bm-tile land on the SAME XCD so the A-tile is fetched once per XCD L2.
// MODE 0: A gathered from obj/pred via edges (K=1536, S|P|O), out -> Dbf (hid)
// MODE 1: split epilogue: col<512  -> atomic f32 add into Dpool at (b,s_idx)
//                         col<1024 -> Df (out_p, f32)
//                         else     -> atomic f32 add into Dpool at (b,o_idx)
//         (fuses the scatter-add half of the mean-pool; normalization happens
//          in MODE 4's staging)
// MODE 3: plain bf16 A -> Df (f32)
// MODE 4: A is f32 (Af) scaled per-row by 1/max(counts,1), reg-staged to LDS
//         (fused pool-normalize), out -> Dbf
template<int MODE, int NBN>
__global__ __launch_bounds__(256, 2) void gemm_k(
    const bf16* __restrict__ A, const bf16* __restrict__ Bt,
    const float* __restrict__ bias, bf16* __restrict__ Dbf,
    float* __restrict__ Df, float* __restrict__ Dpool,
    const int* __restrict__ edges, const bf16* __restrict__ obj,
    const bf16* __restrict__ pred, const float* __restrict__ Af,
    const int* __restrict__ counts, int K)
{
    const int tid = threadIdx.x;
    const int id = blockIdx.x;
    const int bn = (id >> 3) % NBN;
    const int bm = (id & 7) + 8 * ((id >> 3) / NBN);

    __shared__ __align__(16) bf16 ldsA[128 * 64];
    __shared__ __align__(16) bf16 ldsB[128 * 64];

    // staging: thread covers granule flat = tid + 256*i -> row flat>>3, slot tid&7
    const int g_slot = tid & 7;
    const int row0 = tid >> 3;

    unsigned offS[4], offP[4], offO[4], offA[4], offB[4];
    float invc4[4];
#pragma unroll
    for (int i = 0; i < 4; i++) {
        int r = row0 + 32 * i;
        int gr = bm * 128 + r;
        if (MODE == 0) {
            int b = gr >> 9;  // T = 512
            int s = edges[gr * 3 + 0] & 255;
            int o = edges[gr * 3 + 2] & 255;
            offS[i] = (unsigned)(b * 256 + s) * 512u;
            offP[i] = (unsigned)gr * 512u;
            offO[i] = (unsigned)(b * 256 + o) * 512u;
        } else {
            offA[i] = (unsigned)gr * (unsigned)K;
            if (MODE == 4) {
                int c = counts[gr];
                invc4[i] = 1.f / (float)(c > 1 ? c : 1);
            }
        }
        offB[i] = (unsigned)(bn * 128 + r) * (unsigned)K;
    }

    f32x4 acc[4][4];
    const f32x4 zero4 = {0.f, 0.f, 0.f, 0.f};
#pragma unroll
    for (int i = 0; i < 4; i++)
#pragma unroll
        for (int j = 0; j < 4; j++) acc[i][j] = zero4;

    const int wave = tid >> 6;
    const int lane = tid & 63;
    const int wr = (wave >> 1) * 64;
    const int wc = (wave & 1) * 64;
    const int lq = lane >> 4;
    const int lr = lane & 15;

    const int KT = K >> 6;
    for (int kt = 0; kt < KT; ++kt) {
        __syncthreads();  // prior iter's LDS reads complete in all waves
        // stage A: LDS slot (r, g_slot) holds global granule g_slot^(r&7)
#pragma unroll
        for (int i = 0; i < 4; i++) {
            int r = row0 + 32 * i;
            int gsrc = g_slot ^ (r & 7);
            if (MODE == 4) {
                // reg-staged f32 A with fused mean-normalize
                const float* gp = Af + offA[i] + (unsigned)(kt * 64 + gsrc * 8);
                float4 v0 = *(const float4*)gp;
                float4 v1 = *(const float4*)(gp + 4);
                float sc = invc4[i];
                bf16x8 w;
                w[0] = (bf16)(v0.x * sc); w[1] = (bf16)(v0.y * sc);
                w[2] = (bf16)(v0.z * sc); w[3] = (bf16)(v0.w * sc);
                w[4] = (bf16)(v1.x * sc); w[5] = (bf16)(v1.y * sc);
                w[6] = (bf16)(v1.z * sc); w[7] = (bf16)(v1.w * sc);
                *(bf16x8*)(ldsA + (tid + i * 256) * 8) = w;
            } else {
                const bf16* gp;
                if (MODE == 0) {
                    int region = kt >> 3;  // wave-uniform
                    unsigned col = (unsigned)((kt & 7) * 64 + gsrc * 8);
                    if (region == 0)      gp = obj + offS[i] + col;
                    else if (region == 1) gp = pred + offP[i] + col;
                    else                  gp = obj + offO[i] + col;
                } else {
                    gp = A + offA[i] + (unsigned)(kt * 64 + gsrc * 8);
                }
                async_ld16(gp, ldsA + (tid + i * 256) * 8);
            }
        }
#pragma unroll
        for (int i = 0; i < 4; i++) {
            int r = row0 + 32 * i;
            int gsrc = g_slot ^ (r & 7);
            async_ld16(Bt + offB[i] + (unsigned)(kt * 64 + gsrc * 8),
                       ldsB + (tid + i * 256) * 8);
        }
        __syncthreads();  // vmcnt(0)+lgkmcnt(0) drain -> tiles ready

#pragma unroll
        for (int ks = 0; ks < 2; ++ks) {
            bf16x8 af[4], bfr[4];
#pragma unroll
            for (int mi = 0; mi < 4; ++mi) {
                int r = wr + mi * 16 + lr;
                int g = (ks * 4 + lq) ^ (r & 7);
                af[mi] = *(const bf16x8*)(ldsA + (r * 8 + g) * 8);
            }
#pragma unroll
            for (int ni = 0; ni < 4; ++ni) {
                int r = wc + ni * 16 + lr;
                int g = (ks * 4 + lq) ^ (r & 7);
                bfr[ni] = *(const bf16x8*)(ldsB + (r * 8 + g) * 8);
            }
            // swapped operands: D = Bt_frag x A_frag = C^T fragments
#pragma unroll
            for (int mi = 0; mi < 4; ++mi)
#pragma unroll
                for (int ni = 0; ni < 4; ++ni)
                    acc[mi][ni] = __builtin_amdgcn_mfma_f32_16x16x32_bf16(
                        bfr[ni], af[mi], acc[mi][ni], 0, 0, 0);
        }
    }

    // epilogue (swapped layout): row(M) = wr+mi*16+lr, cols(N) = wc+ni*16+lq*4+[0,4)
    unsigned sB[4], oB[4];
    if (MODE == 1) {
#pragma unroll
        for (int mi = 0; mi < 4; ++mi) {
            int row = bm * 128 + wr + mi * 16 + lr;
            int b = row >> 9;  // T = 512
            int s = edges[row * 3 + 0] & 255;
            int o = edges[row * 3 + 2] & 255;
            sB[mi] = (unsigned)((b << 8) + s) * 512u;
            oB[mi] = (unsigned)((b << 8) + o) * 512u;
        }
    }
#pragma unroll
    for (int ni = 0; ni < 4; ++ni) {
        int col = bn * 128 + wc + ni * 16 + lq * 4;
        const f32x4 bv = *(const f32x4*)(bias + col);
#pragma unroll
        for (int mi = 0; mi < 4; ++mi) {
            int row = bm * 128 + wr + mi * 16 + lr;
            f32x4 v = acc[mi][ni];
            f32x4 x;
#pragma unroll
            for (int r = 0; r < 4; r++) {
                float t = v[r] + bv[r];
                x[r] = t > 0.f ? t : 0.f;
            }
            if (MODE == 1) {
                if (col < 512) {
                    float* p = Dpool + sB[mi] + col;
                    atomic_add_f32_dev(p + 0, x[0]);
                    atomic_add_f32_dev(p + 1, x[1]);
                    atomic_add_f32_dev(p + 2, x[2]);
                    atomic_add_f32_dev(p + 3, x[3]);
                } else if (col < 1024) {
                    *(f32x4*)(Df + row * 512 + (col - 512)) = x;
                } else {
                    float* p = Dpool + oB[mi] + (col - 1024);
                    atomic_add_f32_dev(p + 0, x[0]);
                    atomic_add_f32_dev(p + 1, x[1]);
                    atomic_add_f32_dev(p + 2, x[2]);
                    atomic_add_f32_dev(p + 3, x[3]);
                }
            } else if (MODE == 3) {
                *(f32x4*)(Df + row * 512 + col) = x;
            } else {
                bf16x4 o = { (bf16)x[0], (bf16)x[1], (bf16)x[2], (bf16)x[3] };
                *(bf16x4*)(Dbf + row * 512 + col) = o;
            }
        }
    }
}

// fused f32 -> bf16 for obj (2,097,152 float4) + pred (4,194,304 float4),
// plus (blocks >= 24576) per-batch edge-degree counts via LDS histogram.
__global__ void cvt2_k(const float4* __restrict__ o, const float4* __restrict__ p,
                       bf16x4* __restrict__ ob, bf16x4* __restrict__ pb,
                       const int* __restrict__ edges, int* __restrict__ counts_g) {
    int blk = blockIdx.x;
    int t = threadIdx.x;
    if (blk >= 24576) {
        __shared__ int cnt[256];
        int b = blk - 24576;
        cnt[t] = 0;
        __syncthreads();
#pragma unroll
        for (int e = 0; e < 2; e++) {
            int row = b * 512 + t + e * 256;
            atomicAdd(&cnt[edges[row * 3 + 0] & 255], 1);
            atomicAdd(&cnt[edges[row * 3 + 2] & 255], 1);
        }
        __syncthreads();
        counts_g[b * 256 + t] = cnt[t];
        return;
    }
    int i = blk * 256 + t;
    if (i < 2097152) {
        float4 v = o[i];
        bf16x4 r = { (bf16)v.x, (bf16)v.y, (bf16)v.z, (bf16)v.w };
        ob[i] = r;
    } else {
        int j = i - 2097152;
        float4 v = p[j];
        bf16x4 r = { (bf16)v.x, (bf16)v.y, (bf16)v.z, (bf16)v.w };
        pb[j] = r;
    }
}

// fused transpose of all 4 weights: f32 src (R x C) -> bf16 dst (C x R)
__global__ void transpose4_k(const float* __restrict__ w1, bf16* __restrict__ w1t,
                             const float* __restrict__ w2, bf16* __restrict__ w2t,
                             const float* __restrict__ w3, bf16* __restrict__ w3t,
                             const float* __restrict__ w4, bf16* __restrict__ w4t) {
    __shared__ float tile[32][33];
    int id = blockIdx.x;
    const float* src; bf16* dst; int R, C, bx, by;
    if (id < 768)       { src = w1; dst = w1t; R = 1536; C = 512;  bx = id % 16; by = id / 16; }
    else if (id < 1536) { id -= 768;  src = w2; dst = w2t; R = 512; C = 1536; bx = id % 48; by = id / 48; }
    else if (id < 1792) { id -= 1536; src = w3; dst = w3t; R = 512; C = 512;  bx = id % 16; by = id / 16; }
    else                { id -= 1792; src = w4; dst = w4t; R = 512; C = 512;  bx = id % 16; by = id / 16; }
    int c0 = bx * 32, r0 = by * 32;
    int tx = threadIdx.x, ty = threadIdx.y;  // (32,8)
#pragma unroll
    for (int i = 0; i < 4; i++)
        tile[ty + i * 8][tx] = src[(size_t)(r0 + ty + i * 8) * C + c0 + tx];
    __syncthreads();
#pragma unroll
    for (int i = 0; i < 4; i++)
        dst[(size_t)(c0 + ty + i * 8) * R + r0 + tx] = (bf16)tile[tx][ty + i * 8];
}

extern "C" void kernel_launch(void* const* d_in, const int* in_sizes, int n_in,
                              void* d_out, int out_size, void* d_ws, size_t ws_size,
                              hipStream_t stream) {
    const float* obj_f  = (const float*)d_in[0];
    const float* pred_f = (const float*)d_in[1];
    const int*   edges  = (const int*)d_in[2];
    const float* w1 = (const float*)d_in[3];
    const float* b1 = (const float*)d_in[4];
    const float* w2 = (const float*)d_in[5];
    const float* b2 = (const float*)d_in[6];
    const float* w3 = (const float*)d_in[7];
    const float* b3 = (const float*)d_in[8];
    const float* w4 = (const float*)d_in[9];
    const float* b4 = (const float*)d_in[10];

    // workspace layout — ~84 MB
    char* ws = (char*)d_ws;
    bf16* obj_bf  = (bf16*)(ws + 0);            // 16 MB   [dead after gemm1]
    bf16* pred_bf = (bf16*)(ws + 16777216);     // 32 MB   [16MB..48MB, dead after gemm1]
    float* pooled = (float*)(ws + 0);           // 32 MB f32 accum, overlays obj/pred
                                                // (zeroed between gemm1 and gemm2)
    bf16* w1t = (bf16*)(ws + 50331648);         // 512 x 1536
    bf16* w2t = (bf16*)(ws + 51904512);         // 1536 x 512
    bf16* w3t = (bf16*)(ws + 53477376);         // 512 x 512
    bf16* w4t = (bf16*)(ws + 54001664);         // 512 x 512
    bf16* hid = (bf16*)(ws + 54525952);         // 32768 x 512 (32 MB) [dead after gemm2]
    bf16* h2  = (bf16*)(ws + 71303168);         // 16 MB

    float* out_obj = (float*)d_out;             // 64*256*512 f32 (33.5 MB)
    float* out_p   = (float*)d_out + 8388608;   // 64*512*512 f32
    // counts scratch lives in the first 64 KB of out_obj: written by cvt2_k,
    // read by gemm3, overwritten by gemm4's final stores (stream-ordered).
    // (Must NOT live in ws < 48 MB: that region is pred_bf while cvt2_k runs.)
    int* counts    = (int*)d_out;               // 64*256 ints (64 KB)

    // cvt obj/pred to bf16 + per-(b,n) counts (64 extra blocks)
    cvt2_k<<<24640, 256, 0, stream>>>((const float4*)obj_f, (const float4*)pred_f,
                                      (bf16x4*)obj_bf, (bf16x4*)pred_bf,
                                      edges, counts);
    transpose4_k<<<2048, dim3(32, 8), 0, stream>>>(w1, w1t, w2, w2t, w3, w3t, w4, w4t);

    // gemm1: gathered [obj[s]|pred|obj[o]] (K=1536) -> hid
    gemm_k<0, 4><<<1024, 256, 0, stream>>>(
        nullptr, w1t, b1, hid, nullptr, nullptr, edges, obj_bf, pred_bf,
        nullptr, nullptr, 1536);

    // zero the pooled f32 accumulator (obj_bf/pred_bf dead now)
    hipMemsetAsync(pooled, 0, 33554432, stream);

    // gemm2: hid @ w2t; new_s/new_o scatter-added straight into pooled,
    // out_p stored f32
    gemm_k<1, 12><<<3072, 256, 0, stream>>>(
        hid, w2t, b2, nullptr, out_p, pooled, edges, nullptr, nullptr,
        nullptr, nullptr, 512);

    // gemm3: pooled(f32, /count fused into staging) @ w3t -> h2
    gemm_k<4, 4><<<512, 256, 0, stream>>>(
        nullptr, w3t, b3, h2, nullptr, nullptr, nullptr, nullptr, nullptr,
        pooled, counts, 512);

    // gemm4: h2 @ w4t -> out_obj (f32)
    gemm_k<3, 4><<<512, 256, 0, stream>>>(
        h2, w4t, b4, nullptr, out_obj, nullptr, nullptr, nullptr, nullptr,
        nullptr, nullptr, 512);
}

// Round 3
// 535.685 us; speedup vs baseline: 1.4129x; 1.4129x over previous
//
#include <hip/hip_runtime.h>

typedef __bf16 bf16;
typedef __attribute__((ext_vector_type(4))) __bf16 bf16x4;
typedef __attribute__((ext_vector_type(8))) __bf16 bf16x8;
typedef __attribute__((ext_vector_type(4))) float f32x4;

#define DEVINL __device__ __forceinline__

typedef __attribute__((address_space(1))) void gvoid_t;
typedef __attribute__((address_space(3))) void lvoid_t;

DEVINL void async_ld16(const void* g, void* l) {
    __builtin_amdgcn_global_load_lds((gvoid_t*)g, (lvoid_t*)l, 16, 0, 0);
}

// C(M x N) = relu(A(M x K) @ Bt^T + bias); A,Bt bf16; bias f32.
// 128x128 tile, BK=64, 256 threads = 4 waves (2x2 of 64x64), 16x16x32 bf16 MFMA.
// Swapped operands: mfma(bfr, af) -> row(M)=lane&15 in lanes, 4 consecutive
// cols(N) in regs -> vectorized stores.
// 1-D grid + XCD swizzle: id&7 = XCD (round-robin dispatch), all NBN blocks of
// one bm-tile land on the SAME XCD so the A-tile is fetched once per XCD L2.
// MODE 0: A gathered from obj/pred via edges (K=1536, S|P|O), out -> Dbf (hid)
// MODE 1: split: col<512 -> Dbf(new_s); <1024 -> Df(out_p,f32); else Dbf2(new_o)
// MODE 2: plain -> Dbf.  MODE 3: plain -> Df (f32)
template<int MODE, int NBN>
__global__ __launch_bounds__(256, 2) void gemm_k(
    const bf16* __restrict__ A, const bf16* __restrict__ Bt,
    const float* __restrict__ bias, bf16* __restrict__ Dbf,
    float* __restrict__ Df, bf16* __restrict__ Dbf2,
    const int* __restrict__ edges, const bf16* __restrict__ obj,
    const bf16* __restrict__ pred, int K)
{
    const int tid = threadIdx.x;
    const int id = blockIdx.x;
    const int bn = (id >> 3) % NBN;
    const int bm = (id & 7) + 8 * ((id >> 3) / NBN);

    __shared__ __align__(16) bf16 ldsA[128 * 64];
    __shared__ __align__(16) bf16 ldsB[128 * 64];

    // staging: thread covers granule flat = tid + 256*i -> row flat>>3, slot tid&7
    const int g_slot = tid & 7;
    const int row0 = tid >> 3;

    unsigned offS[4], offP[4], offO[4], offA[4], offB[4];
#pragma unroll
    for (int i = 0; i < 4; i++) {
        int r = row0 + 32 * i;
        int gr = bm * 128 + r;
        if (MODE == 0) {
            int b = gr >> 9;  // T = 512
            int s = edges[gr * 3 + 0] & 255;
            int o = edges[gr * 3 + 2] & 255;
            offS[i] = (unsigned)(b * 256 + s) * 512u;
            offP[i] = (unsigned)gr * 512u;
            offO[i] = (unsigned)(b * 256 + o) * 512u;
        } else {
            offA[i] = (unsigned)gr * (unsigned)K;
        }
        offB[i] = (unsigned)(bn * 128 + r) * (unsigned)K;
    }

    f32x4 acc[4][4];
    const f32x4 zero4 = {0.f, 0.f, 0.f, 0.f};
#pragma unroll
    for (int i = 0; i < 4; i++)
#pragma unroll
        for (int j = 0; j < 4; j++) acc[i][j] = zero4;

    const int wave = tid >> 6;
    const int lane = tid & 63;
    const int wr = (wave >> 1) * 64;
    const int wc = (wave & 1) * 64;
    const int lq = lane >> 4;
    const int lr = lane & 15;

    const int KT = K >> 6;
    for (int kt = 0; kt < KT; ++kt) {
        __syncthreads();  // prior iter's LDS reads complete in all waves
        // stage A: LDS slot (r, g_slot) holds global granule g_slot^(r&7)
#pragma unroll
        for (int i = 0; i < 4; i++) {
            int r = row0 + 32 * i;
            int gsrc = g_slot ^ (r & 7);
            const bf16* gp;
            if (MODE == 0) {
                int region = kt >> 3;  // wave-uniform
                unsigned col = (unsigned)((kt & 7) * 64 + gsrc * 8);
                if (region == 0)      gp = obj + offS[i] + col;
                else if (region == 1) gp = pred + offP[i] + col;
                else                  gp = obj + offO[i] + col;
            } else {
                gp = A + offA[i] + (unsigned)(kt * 64 + gsrc * 8);
            }
            async_ld16(gp, ldsA + (tid + i * 256) * 8);
        }
#pragma unroll
        for (int i = 0; i < 4; i++) {
            int r = row0 + 32 * i;
            int gsrc = g_slot ^ (r & 7);
            async_ld16(Bt + offB[i] + (unsigned)(kt * 64 + gsrc * 8),
                       ldsB + (tid + i * 256) * 8);
        }
        __syncthreads();  // vmcnt(0) drain -> tiles ready

#pragma unroll
        for (int ks = 0; ks < 2; ++ks) {
            bf16x8 af[4], bfr[4];
#pragma unroll
            for (int mi = 0; mi < 4; ++mi) {
                int r = wr + mi * 16 + lr;
                int g = (ks * 4 + lq) ^ (r & 7);
                af[mi] = *(const bf16x8*)(ldsA + (r * 8 + g) * 8);
            }
#pragma unroll
            for (int ni = 0; ni < 4; ++ni) {
                int r = wc + ni * 16 + lr;
                int g = (ks * 4 + lq) ^ (r & 7);
                bfr[ni] = *(const bf16x8*)(ldsB + (r * 8 + g) * 8);
            }
            // swapped operands: D = Bt_frag x A_frag = C^T fragments
#pragma unroll
            for (int mi = 0; mi < 4; ++mi)
#pragma unroll
                for (int ni = 0; ni < 4; ++ni)
                    acc[mi][ni] = __builtin_amdgcn_mfma_f32_16x16x32_bf16(
                        bfr[ni], af[mi], acc[mi][ni], 0, 0, 0);
        }
    }

    // epilogue (swapped layout): row(M) = wr+mi*16+lr, cols(N) = wc+ni*16+lq*4+[0,4)
#pragma unroll
    for (int ni = 0; ni < 4; ++ni) {
        int col = bn * 128 + wc + ni * 16 + lq * 4;
        const f32x4 bv = *(const f32x4*)(bias + col);
#pragma unroll
        for (int mi = 0; mi < 4; ++mi) {
            int row = bm * 128 + wr + mi * 16 + lr;
            f32x4 v = acc[mi][ni];
            f32x4 x;
#pragma unroll
            for (int r = 0; r < 4; r++) {
                float t = v[r] + bv[r];
                x[r] = t > 0.f ? t : 0.f;
            }
            if (MODE == 1) {
                if (col < 512) {
                    bf16x4 o = { (bf16)x[0], (bf16)x[1], (bf16)x[2], (bf16)x[3] };
                    *(bf16x4*)(Dbf + row * 512 + col) = o;
                } else if (col < 1024) {
                    *(f32x4*)(Df + row * 512 + (col - 512)) = x;
                } else {
                    bf16x4 o = { (bf16)x[0], (bf16)x[1], (bf16)x[2], (bf16)x[3] };
                    *(bf16x4*)(Dbf2 + row * 512 + (col - 1024)) = o;
                }
            } else if (MODE == 3) {
                *(f32x4*)(Df + row * 512 + col) = x;
            } else {
                bf16x4 o = { (bf16)x[0], (bf16)x[1], (bf16)x[2], (bf16)x[3] };
                *(bf16x4*)(Dbf + row * 512 + col) = o;
            }
        }
    }
}

// Fused preprocessing:
//   blocks [0, 24576):      f32 -> bf16 cvt for obj (2,097,152 float4) then
//                           pred (4,194,304 float4)
//   blocks [24576, 26624):  transpose of the 4 weight matrices f32->bf16
__global__ void pre_k(const float4* __restrict__ o, const float4* __restrict__ p,
                      bf16x4* __restrict__ ob, bf16x4* __restrict__ pb,
                      const float* __restrict__ w1, bf16* __restrict__ w1t,
                      const float* __restrict__ w2, bf16* __restrict__ w2t,
                      const float* __restrict__ w3, bf16* __restrict__ w3t,
                      const float* __restrict__ w4, bf16* __restrict__ w4t) {
    __shared__ float tile[32][33];
    int blk = blockIdx.x;
    int t = threadIdx.x;
    if (blk >= 24576) {
        int id = blk - 24576;
        const float* src; bf16* dst; int R, C, bx, by;
        if (id < 768)       { src = w1; dst = w1t; R = 1536; C = 512;  bx = id % 16; by = id / 16; }
        else if (id < 1536) { id -= 768;  src = w2; dst = w2t; R = 512; C = 1536; bx = id % 48; by = id / 48; }
        else if (id < 1792) { id -= 1536; src = w3; dst = w3t; R = 512; C = 512;  bx = id % 16; by = id / 16; }
        else                { id -= 1792; src = w4; dst = w4t; R = 512; C = 512;  bx = id % 16; by = id / 16; }
        int c0 = bx * 32, r0 = by * 32;
        int tx = t & 31, ty = t >> 5;  // (32,8)
#pragma unroll
        for (int i = 0; i < 4; i++)
            tile[ty + i * 8][tx] = src[(size_t)(r0 + ty + i * 8) * C + c0 + tx];
        __syncthreads();
#pragma unroll
        for (int i = 0; i < 4; i++)
            dst[(size_t)(c0 + ty + i * 8) * R + r0 + tx] = (bf16)tile[tx][ty + i * 8];
        return;
    }
    int i = blk * 256 + t;
    if (i < 2097152) {
        float4 v = o[i];
        bf16x4 r = { (bf16)v.x, (bf16)v.y, (bf16)v.z, (bf16)v.w };
        ob[i] = r;
    } else {
        int j = i - 2097152;
        float4 v = p[j];
        bf16x4 r = { (bf16)v.x, (bf16)v.y, (bf16)v.z, (bf16)v.w };
        pb[j] = r;
    }
}

// Fused scatter-mean pooling, all accumulation in LDS (native ds_add_f32).
// Grid: 512 blocks = (batch b = id>>3) x (64-col chunk ch = id&7), 256 threads.
// LDS: acc[256 nodes][64 cols] f32 (64 KB) -> 2 blocks/CU.
// Each new_s/new_o byte is read exactly once device-wide (64 MB total),
// output pooled bf16 written once (16 MB). Replaces csr_k + pool_k.
__global__ __launch_bounds__(256, 2) void pool2_k(
    const int* __restrict__ edges,
    const bf16* __restrict__ new_s, const bf16* __restrict__ new_o,
    bf16* __restrict__ out) {
    __shared__ float acc[256 * 64];
    __shared__ int sidx[512], oidx[512];
    __shared__ int cnt[256];
    const int b = blockIdx.x >> 3;
    const int ch = blockIdx.x & 7;
    const int t = threadIdx.x;

#pragma unroll
    for (int i = 0; i < 64; i++) acc[t + i * 256] = 0.f;
    cnt[t] = 0;
    __syncthreads();

#pragma unroll
    for (int e0 = 0; e0 < 2; e0++) {
        int e = t + e0 * 256;
        int row = b * 512 + e;
        int s = edges[row * 3 + 0] & 255;
        int o = edges[row * 3 + 2] & 255;
        sidx[e] = s;
        oidx[e] = o;
        atomicAdd(&cnt[s], 1);
        atomicAdd(&cnt[o], 1);
    }
    __syncthreads();

    // wave wv sweeps triples wv, wv+4, ...; lane = col within chunk
    const int wv = t >> 6, ln = t & 63;
    const unsigned c = (unsigned)(ch * 64 + ln);
    for (int e = wv; e < 512; e += 4) {
        unsigned row = (unsigned)(b * 512 + e);
        float vs = (float)new_s[row * 512u + c];
        atomicAdd(&acc[sidx[e] * 64 + ln], vs);
        float vo = (float)new_o[row * 512u + c];
        atomicAdd(&acc[oidx[e] * 64 + ln], vo);
    }
    __syncthreads();

    // write 256x64 bf16, mean-normalized; coalesced 128B per wave
#pragma unroll
    for (int i = 0; i < 64; i++) {
        int idx = i * 256 + t;
        int n = idx >> 6, col = idx & 63;
        int cn = cnt[n];
        float inv = 1.f / (float)(cn > 1 ? cn : 1);
        out[(unsigned)(b * 256 + n) * 512u + (unsigned)(ch * 64 + col)] =
            (bf16)(acc[idx] * inv);
    }
}

extern "C" void kernel_launch(void* const* d_in, const int* in_sizes, int n_in,
                              void* d_out, int out_size, void* d_ws, size_t ws_size,
                              hipStream_t stream) {
    const float* obj_f  = (const float*)d_in[0];
    const float* pred_f = (const float*)d_in[1];
    const int*   edges  = (const int*)d_in[2];
    const float* w1 = (const float*)d_in[3];
    const float* b1 = (const float*)d_in[4];
    const float* w2 = (const float*)d_in[5];
    const float* b2 = (const float*)d_in[6];
    const float* w3 = (const float*)d_in[7];
    const float* b3 = (const float*)d_in[8];
    const float* w4 = (const float*)d_in[9];
    const float* b4 = (const float*)d_in[10];

    // workspace layout — 88 MB
    char* ws = (char*)d_ws;
    bf16* obj_bf  = (bf16*)(ws + 0);            // 16 MB   [dead after gemm1]
    bf16* pred_bf = (bf16*)(ws + 16777216);     // 32 MB   [dead after gemm1]
    bf16* new_s   = (bf16*)(ws + 0);            // 32 MB   overlays obj/pred
    bf16* w1t = (bf16*)(ws + 50331648);         // 512 x 1536
    bf16* w2t = (bf16*)(ws + 51904512);         // 1536 x 512
    bf16* w3t = (bf16*)(ws + 53477376);         // 512 x 512
    bf16* w4t = (bf16*)(ws + 54001664);         // 512 x 512
    bf16* hid = (bf16*)(ws + 54525952);         // 32768 x 512 (32 MB) [dead after gemm2]
    bf16* pooled_bf = hid;                      // 16 MB, reuse after gemm2
    bf16* h2  = (bf16*)(ws + 71303168);         // 16 MB

    float* out_obj = (float*)d_out;             // 64*256*512 f32 (33.5 MB)
    float* out_p   = (float*)d_out + 8388608;   // 64*512*512 f32
    bf16* new_o    = (bf16*)d_out;              // 32 MB scratch in out_obj region;
                                                // overwritten by gemm4 at the end

    // cvt obj/pred to bf16 + weight transposes (fused)
    pre_k<<<26624, 256, 0, stream>>>((const float4*)obj_f, (const float4*)pred_f,
                                     (bf16x4*)obj_bf, (bf16x4*)pred_bf,
                                     w1, w1t, w2, w2t, w3, w3t, w4, w4t);

    // gemm1: gathered [obj[s]|pred|obj[o]] (K=1536) -> hid
    gemm_k<0, 4><<<1024, 256, 0, stream>>>(
        nullptr, w1t, b1, hid, nullptr, nullptr, edges, obj_bf, pred_bf, 1536);

    // gemm2: hid @ w2t -> new_s | out_p | new_o
    gemm_k<1, 12><<<3072, 256, 0, stream>>>(
        hid, w2t, b2, new_s, out_p, new_o, nullptr, nullptr, nullptr, 512);

    // fused scatter-mean pool (replaces csr_k + pool_k)
    pool2_k<<<512, 256, 0, stream>>>(edges, new_s, new_o, pooled_bf);

    // gemm3: pooled @ w3t -> h2
    gemm_k<2, 4><<<512, 256, 0, stream>>>(
        pooled_bf, w3t, b3, h2, nullptr, nullptr, nullptr, nullptr, nullptr, 512);

    // gemm4: h2 @ w4t -> out_obj (f32)
    gemm_k<3, 4><<<512, 256, 0, stream>>>(
        h2, w4t, b4, nullptr, out_obj, nullptr, nullptr, nullptr, nullptr, 512);
}

// Round 4
// 380.864 us; speedup vs baseline: 1.9872x; 1.4065x over previous
//
#include <hip/hip_runtime.h>

typedef __bf16 bf16;
typedef __attribute__((ext_vector_type(2))) __bf16 bf16x2;
typedef __attribute__((ext_vector_type(4))) __bf16 bf16x4;
typedef __attribute__((ext_vector_type(8))) __bf16 bf16x8;
typedef __attribute__((ext_vector_type(4))) float f32x4;

#define DEVINL __device__ __forceinline__

typedef __attribute__((address_space(1))) void gvoid_t;
typedef __attribute__((address_space(3))) void lvoid_t;

DEVINL void async_ld16(const void* g, void* l) {
    __builtin_amdgcn_global_load_lds((gvoid_t*)g, (lvoid_t*)l, 16, 0, 0);
}

// C(M x N) = relu(A(M x K) @ Bt^T + bias); A,Bt bf16; bias f32.
// 128x128 tile, BK=64, 256 threads = 4 waves (2x2 of 64x64), 16x16x32 bf16 MFMA.
// Swapped operands: mfma(bfr, af) -> row(M)=lane&15 in lanes, 4 consecutive
// cols(N) in regs -> vectorized stores.
// 1-D grid + XCD swizzle: id&7 = XCD (round-robin dispatch), all NBN blocks of
// one bm-tile land on the SAME XCD so the A-tile is fetched once per XCD L2.
// MODE 0: A gathered from obj/pred via edges (K=1536, S|P|O), out -> Dbf (hid)
// MODE 1: split: col<512 -> Dbf(new_s); <1024 -> Df(out_p,f32); else Dbf2(new_o)
// MODE 2: plain -> Dbf.  MODE 3: plain -> Df (f32)
template<int MODE, int NBN>
__global__ __launch_bounds__(256, 2) void gemm_k(
    const bf16* __restrict__ A, const bf16* __restrict__ Bt,
    const float* __restrict__ bias, bf16* __restrict__ Dbf,
    float* __restrict__ Df, bf16* __restrict__ Dbf2,
    const int* __restrict__ edges, const bf16* __restrict__ obj,
    const bf16* __restrict__ pred, int K)
{
    const int tid = threadIdx.x;
    const int id = blockIdx.x;
    const int bn = (id >> 3) % NBN;
    const int bm = (id & 7) + 8 * ((id >> 3) / NBN);

    __shared__ __align__(16) bf16 ldsA[128 * 64];
    __shared__ __align__(16) bf16 ldsB[128 * 64];

    // staging: thread covers granule flat = tid + 256*i -> row flat>>3, slot tid&7
    const int g_slot = tid & 7;
    const int row0 = tid >> 3;

    unsigned offS[4], offP[4], offO[4], offA[4], offB[4];
#pragma unroll
    for (int i = 0; i < 4; i++) {
        int r = row0 + 32 * i;
        int gr = bm * 128 + r;
        if (MODE == 0) {
            int b = gr >> 9;  // T = 512
            int s = edges[gr * 3 + 0] & 255;
            int o = edges[gr * 3 + 2] & 255;
            offS[i] = (unsigned)(b * 256 + s) * 512u;
            offP[i] = (unsigned)gr * 512u;
            offO[i] = (unsigned)(b * 256 + o) * 512u;
        } else {
            offA[i] = (unsigned)gr * (unsigned)K;
        }
        offB[i] = (unsigned)(bn * 128 + r) * (unsigned)K;
    }

    f32x4 acc[4][4];
    const f32x4 zero4 = {0.f, 0.f, 0.f, 0.f};
#pragma unroll
    for (int i = 0; i < 4; i++)
#pragma unroll
        for (int j = 0; j < 4; j++) acc[i][j] = zero4;

    const int wave = tid >> 6;
    const int lane = tid & 63;
    const int wr = (wave >> 1) * 64;
    const int wc = (wave & 1) * 64;
    const int lq = lane >> 4;
    const int lr = lane & 15;

    const int KT = K >> 6;
    for (int kt = 0; kt < KT; ++kt) {
        __syncthreads();  // prior iter's LDS reads complete in all waves
        // stage A: LDS slot (r, g_slot) holds global granule g_slot^(r&7)
#pragma unroll
        for (int i = 0; i < 4; i++) {
            int r = row0 + 32 * i;
            int gsrc = g_slot ^ (r & 7);
            const bf16* gp;
            if (MODE == 0) {
                int region = kt >> 3;  // wave-uniform
                unsigned col = (unsigned)((kt & 7) * 64 + gsrc * 8);
                if (region == 0)      gp = obj + offS[i] + col;
                else if (region == 1) gp = pred + offP[i] + col;
                else                  gp = obj + offO[i] + col;
            } else {
                gp = A + offA[i] + (unsigned)(kt * 64 + gsrc * 8);
            }
            async_ld16(gp, ldsA + (tid + i * 256) * 8);
        }
#pragma unroll
        for (int i = 0; i < 4; i++) {
            int r = row0 + 32 * i;
            int gsrc = g_slot ^ (r & 7);
            async_ld16(Bt + offB[i] + (unsigned)(kt * 64 + gsrc * 8),
                       ldsB + (tid + i * 256) * 8);
        }
        __syncthreads();  // vmcnt(0) drain -> tiles ready

#pragma unroll
        for (int ks = 0; ks < 2; ++ks) {
            bf16x8 af[4], bfr[4];
#pragma unroll
            for (int mi = 0; mi < 4; ++mi) {
                int r = wr + mi * 16 + lr;
                int g = (ks * 4 + lq) ^ (r & 7);
                af[mi] = *(const bf16x8*)(ldsA + (r * 8 + g) * 8);
            }
#pragma unroll
            for (int ni = 0; ni < 4; ++ni) {
                int r = wc + ni * 16 + lr;
                int g = (ks * 4 + lq) ^ (r & 7);
                bfr[ni] = *(const bf16x8*)(ldsB + (r * 8 + g) * 8);
            }
            // swapped operands: D = Bt_frag x A_frag = C^T fragments
#pragma unroll
            for (int mi = 0; mi < 4; ++mi)
#pragma unroll
                for (int ni = 0; ni < 4; ++ni)
                    acc[mi][ni] = __builtin_amdgcn_mfma_f32_16x16x32_bf16(
                        bfr[ni], af[mi], acc[mi][ni], 0, 0, 0);
        }
    }

    // epilogue (swapped layout): row(M) = wr+mi*16+lr, cols(N) = wc+ni*16+lq*4+[0,4)
#pragma unroll
    for (int ni = 0; ni < 4; ++ni) {
        int col = bn * 128 + wc + ni * 16 + lq * 4;
        const f32x4 bv = *(const f32x4*)(bias + col);
#pragma unroll
        for (int mi = 0; mi < 4; ++mi) {
            int row = bm * 128 + wr + mi * 16 + lr;
            f32x4 v = acc[mi][ni];
            f32x4 x;
#pragma unroll
            for (int r = 0; r < 4; r++) {
                float t = v[r] + bv[r];
                x[r] = t > 0.f ? t : 0.f;
            }
            if (MODE == 1) {
                if (col < 512) {
                    bf16x4 o = { (bf16)x[0], (bf16)x[1], (bf16)x[2], (bf16)x[3] };
                    *(bf16x4*)(Dbf + row * 512 + col) = o;
                } else if (col < 1024) {
                    *(f32x4*)(Df + row * 512 + (col - 512)) = x;
                } else {
                    bf16x4 o = { (bf16)x[0], (bf16)x[1], (bf16)x[2], (bf16)x[3] };
                    *(bf16x4*)(Dbf2 + row * 512 + (col - 1024)) = o;
                }
            } else if (MODE == 3) {
                *(f32x4*)(Df + row * 512 + col) = x;
            } else {
                bf16x4 o = { (bf16)x[0], (bf16)x[1], (bf16)x[2], (bf16)x[3] };
                *(bf16x4*)(Dbf + row * 512 + col) = o;
            }
        }
    }
}

// Fused preprocessing:
//   blocks [0, 24576):      f32 -> bf16 cvt for obj (2,097,152 float4) then
//                           pred (4,194,304 float4)
//   blocks [24576, 26624):  transpose of the 4 weight matrices f32->bf16
__global__ void pre_k(const float4* __restrict__ o, const float4* __restrict__ p,
                      bf16x4* __restrict__ ob, bf16x4* __restrict__ pb,
                      const float* __restrict__ w1, bf16* __restrict__ w1t,
                      const float* __restrict__ w2, bf16* __restrict__ w2t,
                      const float* __restrict__ w3, bf16* __restrict__ w3t,
                      const float* __restrict__ w4, bf16* __restrict__ w4t) {
    __shared__ float tile[32][33];
    int blk = blockIdx.x;
    int t = threadIdx.x;
    if (blk >= 24576) {
        int id = blk - 24576;
        const float* src; bf16* dst; int R, C, bx, by;
        if (id < 768)       { src = w1; dst = w1t; R = 1536; C = 512;  bx = id % 16; by = id / 16; }
        else if (id < 1536) { id -= 768;  src = w2; dst = w2t; R = 512; C = 1536; bx = id % 48; by = id / 48; }
        else if (id < 1792) { id -= 1536; src = w3; dst = w3t; R = 512; C = 512;  bx = id % 16; by = id / 16; }
        else                { id -= 1792; src = w4; dst = w4t; R = 512; C = 512;  bx = id % 16; by = id / 16; }
        int c0 = bx * 32, r0 = by * 32;
        int tx = t & 31, ty = t >> 5;  // (32,8)
#pragma unroll
        for (int i = 0; i < 4; i++)
            tile[ty + i * 8][tx] = src[(size_t)(r0 + ty + i * 8) * C + c0 + tx];
        __syncthreads();
#pragma unroll
        for (int i = 0; i < 4; i++)
            dst[(size_t)(c0 + ty + i * 8) * R + r0 + tx] = (bf16)tile[tx][ty + i * 8];
        return;
    }
    int i = blk * 256 + t;
    if (i < 2097152) {
        float4 v = o[i];
        bf16x4 r = { (bf16)v.x, (bf16)v.y, (bf16)v.z, (bf16)v.w };
        ob[i] = r;
    } else {
        int j = i - 2097152;
        float4 v = p[j];
        bf16x4 r = { (bf16)v.x, (bf16)v.y, (bf16)v.z, (bf16)v.w };
        pb[j] = r;
    }
}

// Self-contained scatter-mean pooling (replaces csr_k + pool_k).
// One block per (b, n): scan batch b's 512 triples (edges are L2/L3-hot,
// 384 KB device-wide) to build this node's entry list in LDS, then gather-mean
// the matching new_s/new_o rows with bf16x2 vectorized loads.
// 16384 blocks -> latency hidden by TLP; each new_s/new_o row read exactly
// once device-wide for s and once for o (64 MB total), out 16 MB written once.
__global__ __launch_bounds__(256) void pool3_k(
    const int* __restrict__ edges,
    const bf16* __restrict__ new_s, const bf16* __restrict__ new_o,
    bf16* __restrict__ out)
{
    __shared__ int ent[1024];
    __shared__ int ec;
    const int idx = blockIdx.x;
    const int b = idx >> 8, n = idx & 255;
    const int t = threadIdx.x;
    if (t == 0) ec = 0;
    __syncthreads();
#pragma unroll
    for (int e0 = 0; e0 < 2; e0++) {
        int row = b * 512 + t + e0 * 256;
        int s = edges[row * 3 + 0] & 255;
        int o = edges[row * 3 + 2] & 255;
        if (s == n) { int ps = atomicAdd(&ec, 1); ent[ps] = row << 1; }
        if (o == n) { int po = atomicAdd(&ec, 1); ent[po] = (row << 1) | 1; }
    }
    __syncthreads();
    const int c = ec;
    float a0 = 0.f, a1 = 0.f;
    for (int j = 0; j < c; ++j) {
        int v = ent[j];
        const bf16x2* rp = (const bf16x2*)(((v & 1) ? new_o : new_s) +
                                           (unsigned)(v >> 1) * 512u);
        bf16x2 w = rp[t];
        a0 += (float)w[0];
        a1 += (float)w[1];
    }
    float inv = 1.f / (float)(c > 1 ? c : 1);
    bf16x2 o2 = { (bf16)(a0 * inv), (bf16)(a1 * inv) };
    *(bf16x2*)(out + (unsigned)idx * 512u + (unsigned)(t * 2)) = o2;
}

extern "C" void kernel_launch(void* const* d_in, const int* in_sizes, int n_in,
                              void* d_out, int out_size, void* d_ws, size_t ws_size,
                              hipStream_t stream) {
    const float* obj_f  = (const float*)d_in[0];
    const float* pred_f = (const float*)d_in[1];
    const int*   edges  = (const int*)d_in[2];
    const float* w1 = (const float*)d_in[3];
    const float* b1 = (const float*)d_in[4];
    const float* w2 = (const float*)d_in[5];
    const float* b2 = (const float*)d_in[6];
    const float* w3 = (const float*)d_in[7];
    const float* b3 = (const float*)d_in[8];
    const float* w4 = (const float*)d_in[9];
    const float* b4 = (const float*)d_in[10];

    // workspace layout — 88 MB
    char* ws = (char*)d_ws;
    bf16* obj_bf  = (bf16*)(ws + 0);            // 16 MB   [dead after gemm1]
    bf16* pred_bf = (bf16*)(ws + 16777216);     // 32 MB   [dead after gemm1]
    bf16* new_s   = (bf16*)(ws + 0);            // 32 MB   overlays obj/pred
    bf16* w1t = (bf16*)(ws + 50331648);         // 512 x 1536
    bf16* w2t = (bf16*)(ws + 51904512);         // 1536 x 512
    bf16* w3t = (bf16*)(ws + 53477376);         // 512 x 512
    bf16* w4t = (bf16*)(ws + 54001664);         // 512 x 512
    bf16* hid = (bf16*)(ws + 54525952);         // 32768 x 512 (32 MB) [dead after gemm2]
    bf16* pooled_bf = hid;                      // 16 MB, reuse after gemm2
    bf16* h2  = (bf16*)(ws + 71303168);         // 16 MB

    float* out_obj = (float*)d_out;             // 64*256*512 f32 (32 MiB)
    float* out_p   = (float*)d_out + 8388608;   // 64*512*512 f32
    bf16* new_o    = (bf16*)d_out;              // 32 MiB scratch in out_obj region;
                                                // overwritten by gemm4 at the end

    // cvt obj/pred to bf16 + weight transposes (fused)
    pre_k<<<26624, 256, 0, stream>>>((const float4*)obj_f, (const float4*)pred_f,
                                     (bf16x4*)obj_bf, (bf16x4*)pred_bf,
                                     w1, w1t, w2, w2t, w3, w3t, w4, w4t);

    // gemm1: gathered [obj[s]|pred|obj[o]] (K=1536) -> hid
    gemm_k<0, 4><<<1024, 256, 0, stream>>>(
        nullptr, w1t, b1, hid, nullptr, nullptr, edges, obj_bf, pred_bf, 1536);

    // gemm2: hid @ w2t -> new_s | out_p | new_o
    gemm_k<1, 12><<<3072, 256, 0, stream>>>(
        hid, w2t, b2, new_s, out_p, new_o, nullptr, nullptr, nullptr, 512);

    // self-contained scatter-mean pool (replaces csr_k + pool_k)
    pool3_k<<<16384, 256, 0, stream>>>(edges, new_s, new_o, pooled_bf);

    // gemm3: pooled @ w3t -> h2
    gemm_k<2, 4><<<512, 256, 0, stream>>>(
        pooled_bf, w3t, b3, h2, nullptr, nullptr, nullptr, nullptr, nullptr, 512);

    // gemm4: h2 @ w4t -> out_obj (f32)
    gemm_k<3, 4><<<512, 256, 0, stream>>>(
        h2, w4t, b4, nullptr, out_obj, nullptr, nullptr, nullptr, nullptr, 512);
}

// Round 5
// 366.961 us; speedup vs baseline: 2.0625x; 1.0379x over previous
//
#include <hip/hip_runtime.h>

typedef __bf16 bf16;
typedef __attribute__((ext_vector_type(2))) __bf16 bf16x2;
typedef __attribute__((ext_vector_type(4))) __bf16 bf16x4;
typedef __attribute__((ext_vector_type(8))) __bf16 bf16x8;
typedef __attribute__((ext_vector_type(4))) float f32x4;

#define DEVINL __device__ __forceinline__

typedef __attribute__((address_space(1))) void gvoid_t;
typedef __attribute__((address_space(3))) void lvoid_t;

DEVINL void async_ld16(const void* g, void* l) {
    __builtin_amdgcn_global_load_lds((gvoid_t*)g, (lvoid_t*)l, 16, 0, 0);
}

// C(M x N) = relu(A(M x K) @ Bt^T + bias); A,Bt bf16; bias f32.
// 128x128 tile, BK=64, 256 threads = 4 waves (2x2 of 64x64), 16x16x32 bf16 MFMA.
// Swapped operands: mfma(bfr, af) -> row(M)=lane&15 in lanes, 4 consecutive
// cols(N) in regs.
// EPILOGUE: acc fragments are staged through LDS (reusing the K-loop buffers,
// XOR-swizzled) and written with fully-coalesced 128B-per-row runs so every
// 64B HBM line is produced by one instruction. (Direct 8B/lane fragment
// stores showed 1.27-1.55x WRITE_SIZE amplification in rocprof.)
// 1-D grid + XCD swizzle: id&7 = XCD (round-robin dispatch), all NBN blocks of
// one bm-tile land on the SAME XCD so the A-tile is fetched once per XCD L2.
// MODE 0: A gathered from obj/pred via edges (K=1536, S|P|O), out -> Dbf (hid)
// MODE 1: block-uniform split by bn (NBN=12): bn<4 -> Dbf(new_s, bf16);
//         bn<8 -> Df(out_p, f32); else -> Dbf2(new_o, bf16)
// MODE 2: plain -> Dbf.  MODE 3: plain -> Df (f32)
template<int MODE, int NBN>
__global__ __launch_bounds__(256, 2) void gemm_k(
    const bf16* __restrict__ A, const bf16* __restrict__ Bt,
    const float* __restrict__ bias, bf16* __restrict__ Dbf,
    float* __restrict__ Df, bf16* __restrict__ Dbf2,
    const int* __restrict__ edges, const bf16* __restrict__ obj,
    const bf16* __restrict__ pred, int K)
{
    const int tid = threadIdx.x;
    const int id = blockIdx.x;
    const int bn = (id >> 3) % NBN;
    const int bm = (id & 7) + 8 * ((id >> 3) / NBN);

    __shared__ __align__(16) bf16 lds[2 * 128 * 64];  // A | B ; reused as C-stage
    bf16* ldsA = lds;
    bf16* ldsB = lds + 128 * 64;

    // staging: thread covers granule flat = tid + 256*i -> row flat>>3, slot tid&7
    const int g_slot = tid & 7;
    const int row0 = tid >> 3;

    unsigned offS[4], offP[4], offO[4], offA[4], offB[4];
#pragma unroll
    for (int i = 0; i < 4; i++) {
        int r = row0 + 32 * i;
        int gr = bm * 128 + r;
        if (MODE == 0) {
            int b = gr >> 9;  // T = 512
            int s = edges[gr * 3 + 0] & 255;
            int o = edges[gr * 3 + 2] & 255;
            offS[i] = (unsigned)(b * 256 + s) * 512u;
            offP[i] = (unsigned)gr * 512u;
            offO[i] = (unsigned)(b * 256 + o) * 512u;
        } else {
            offA[i] = (unsigned)gr * (unsigned)K;
        }
        offB[i] = (unsigned)(bn * 128 + r) * (unsigned)K;
    }

    f32x4 acc[4][4];
    const f32x4 zero4 = {0.f, 0.f, 0.f, 0.f};
#pragma unroll
    for (int i = 0; i < 4; i++)
#pragma unroll
        for (int j = 0; j < 4; j++) acc[i][j] = zero4;

    const int wave = tid >> 6;
    const int lane = tid & 63;
    const int wr = (wave >> 1) * 64;
    const int wc = (wave & 1) * 64;
    const int lq = lane >> 4;
    const int lr = lane & 15;

    const int KT = K >> 6;
    for (int kt = 0; kt < KT; ++kt) {
        __syncthreads();  // prior iter's LDS reads complete in all waves
        // stage A: LDS slot (r, g_slot) holds global granule g_slot^(r&7)
#pragma unroll
        for (int i = 0; i < 4; i++) {
            int r = row0 + 32 * i;
            int gsrc = g_slot ^ (r & 7);
            const bf16* gp;
            if (MODE == 0) {
                int region = kt >> 3;  // wave-uniform
                unsigned col = (unsigned)((kt & 7) * 64 + gsrc * 8);
                if (region == 0)      gp = obj + offS[i] + col;
                else if (region == 1) gp = pred + offP[i] + col;
                else                  gp = obj + offO[i] + col;
            } else {
                gp = A + offA[i] + (unsigned)(kt * 64 + gsrc * 8);
            }
            async_ld16(gp, ldsA + (tid + i * 256) * 8);
        }
#pragma unroll
        for (int i = 0; i < 4; i++) {
            int r = row0 + 32 * i;
            int gsrc = g_slot ^ (r & 7);
            async_ld16(Bt + offB[i] + (unsigned)(kt * 64 + gsrc * 8),
                       ldsB + (tid + i * 256) * 8);
        }
        __syncthreads();  // vmcnt(0) drain -> tiles ready

#pragma unroll
        for (int ks = 0; ks < 2; ++ks) {
            bf16x8 af[4], bfr[4];
#pragma unroll
            for (int mi = 0; mi < 4; ++mi) {
                int r = wr + mi * 16 + lr;
                int g = (ks * 4 + lq) ^ (r & 7);
                af[mi] = *(const bf16x8*)(ldsA + (r * 8 + g) * 8);
            }
#pragma unroll
            for (int ni = 0; ni < 4; ++ni) {
                int r = wc + ni * 16 + lr;
                int g = (ks * 4 + lq) ^ (r & 7);
                bfr[ni] = *(const bf16x8*)(ldsB + (r * 8 + g) * 8);
            }
            // swapped operands: D = Bt_frag x A_frag = C^T fragments
#pragma unroll
            for (int mi = 0; mi < 4; ++mi)
#pragma unroll
                for (int ni = 0; ni < 4; ++ni)
                    acc[mi][ni] = __builtin_amdgcn_mfma_f32_16x16x32_bf16(
                        bfr[ni], af[mi], acc[mi][ni], 0, 0, 0);
        }
    }

    // ---- epilogue via LDS C-staging ----
    __syncthreads();  // K-loop LDS is dead in all waves

    const int rb = bm * 128 + wr;          // global row base of this wave's tile
    const bool f32path = (MODE == 3) || (MODE == 1 && bn >= 4 && bn < 8);

    if (!f32path) {
        // bf16 output: wave-local 64x64 bf16 stage (8 KB per wave)
        bf16* cw = lds + wave * 4096;
        const bf16* /*unused*/ dummy = nullptr; (void)dummy;
        bf16* outp;
        int cb;  // element col base in a 512-wide row
        if (MODE == 1) {
            if (bn < 4) { outp = Dbf;  cb = bn * 128 + wc; }
            else        { outp = Dbf2; cb = bn * 128 + wc - 1024; }
        } else {
            outp = Dbf; cb = bn * 128 + wc;
        }
#pragma unroll
        for (int ni = 0; ni < 4; ++ni) {
            const f32x4 bv = *(const f32x4*)(bias + bn * 128 + wc + ni * 16 + lq * 4);
#pragma unroll
            for (int mi = 0; mi < 4; ++mi) {
                f32x4 v = acc[mi][ni];
                int row = mi * 16 + lr;
                int sl = (ni * 2 + (lq >> 1)) ^ (row & 7);
                bf16x4 o4;
#pragma unroll
                for (int r = 0; r < 4; r++) {
                    float t = v[r] + bv[r];
                    o4[r] = (bf16)(t > 0.f ? t : 0.f);
                }
                *(bf16x4*)(cw + row * 64 + sl * 8 + (lq & 1) * 4) = o4;
            }
        }
        // coalesced copy-out: 8 lanes x 16B = 128B contiguous per row
#pragma unroll
        for (int it = 0; it < 8; ++it) {
            int g = it * 64 + lane;
            int row = g >> 3, k = g & 7;
            bf16x8 v = *(const bf16x8*)(cw + row * 64 + ((k ^ (row & 7)) * 8));
            *(bf16x8*)(outp + (unsigned)(rb + row) * 512u + cb + k * 8) = v;
        }
    } else {
        // f32 output: two passes of 32 rows x 64 cols f32 (8 KB per wave)
        float* cwf = (float*)lds + wave * 2048;
        const int cbf = (MODE == 1) ? (bn * 128 + wc - 512) : (bn * 128 + wc);
#pragma unroll
        for (int half = 0; half < 2; ++half) {
#pragma unroll
            for (int ni = 0; ni < 4; ++ni) {
                const f32x4 bv = *(const f32x4*)(bias + bn * 128 + wc + ni * 16 + lq * 4);
#pragma unroll
                for (int mi2 = 0; mi2 < 2; ++mi2) {
                    f32x4 v = acc[half * 2 + mi2][ni];
                    int row = mi2 * 16 + lr;
                    int s16 = ni * 4 + lq;
                    int sl = (s16 & 8) | ((s16 & 7) ^ (row & 7));
                    f32x4 x;
#pragma unroll
                    for (int r = 0; r < 4; r++) {
                        float t = v[r] + bv[r];
                        x[r] = t > 0.f ? t : 0.f;
                    }
                    *(f32x4*)(cwf + row * 64 + sl * 4) = x;
                }
            }
            // coalesced copy-out: 16 lanes x 16B = 256B contiguous per row
#pragma unroll
            for (int it = 0; it < 8; ++it) {
                int g = it * 64 + lane;
                int row = g >> 4, k = g & 15;
                int kk = (k & 8) | ((k & 7) ^ (row & 7));
                f32x4 v = *(const f32x4*)(cwf + row * 64 + kk * 4);
                *(f32x4*)(Df + (unsigned)(rb + half * 32 + row) * 512u + cbf + k * 4) = v;
            }
        }
    }
}

// Fused preprocessing:
//   blocks [0, 24576):      f32 -> bf16 cvt for obj (2,097,152 float4) then
//                           pred (4,194,304 float4)
//   blocks [24576, 26624):  transpose of the 4 weight matrices f32->bf16
__global__ void pre_k(const float4* __restrict__ o, const float4* __restrict__ p,
                      bf16x4* __restrict__ ob, bf16x4* __restrict__ pb,
                      const float* __restrict__ w1, bf16* __restrict__ w1t,
                      const float* __restrict__ w2, bf16* __restrict__ w2t,
                      const float* __restrict__ w3, bf16* __restrict__ w3t,
                      const float* __restrict__ w4, bf16* __restrict__ w4t) {
    __shared__ float tile[32][33];
    int blk = blockIdx.x;
    int t = threadIdx.x;
    if (blk >= 24576) {
        int id = blk - 24576;
        const float* src; bf16* dst; int R, C, bx, by;
        if (id < 768)       { src = w1; dst = w1t; R = 1536; C = 512;  bx = id % 16; by = id / 16; }
        else if (id < 1536) { id -= 768;  src = w2; dst = w2t; R = 512; C = 1536; bx = id % 48; by = id / 48; }
        else if (id < 1792) { id -= 1536; src = w3; dst = w3t; R = 512; C = 512;  bx = id % 16; by = id / 16; }
        else                { id -= 1792; src = w4; dst = w4t; R = 512; C = 512;  bx = id % 16; by = id / 16; }
        int c0 = bx * 32, r0 = by * 32;
        int tx = t & 31, ty = t >> 5;  // (32,8)
#pragma unroll
        for (int i = 0; i < 4; i++)
            tile[ty + i * 8][tx] = src[(size_t)(r0 + ty + i * 8) * C + c0 + tx];
        __syncthreads();
#pragma unroll
        for (int i = 0; i < 4; i++)
            dst[(size_t)(c0 + ty + i * 8) * R + r0 + tx] = (bf16)tile[tx][ty + i * 8];
        return;
    }
    int i = blk * 256 + t;
    if (i < 2097152) {
        float4 v = o[i];
        bf16x4 r = { (bf16)v.x, (bf16)v.y, (bf16)v.z, (bf16)v.w };
        ob[i] = r;
    } else {
        int j = i - 2097152;
        float4 v = p[j];
        bf16x4 r = { (bf16)v.x, (bf16)v.y, (bf16)v.z, (bf16)v.w };
        pb[j] = r;
    }
}

// Self-contained scatter-mean pooling (replaces csr_k + pool_k).
// One block per (b, n): scan batch b's 512 triples (edges are L2/L3-hot,
// 384 KB device-wide) to build this node's entry list in LDS, then gather-mean
// the matching new_s/new_o rows with bf16x2 vectorized loads.
__global__ __launch_bounds__(256) void pool3_k(
    const int* __restrict__ edges,
    const bf16* __restrict__ new_s, const bf16* __restrict__ new_o,
    bf16* __restrict__ out)
{
    __shared__ int ent[1024];
    __shared__ int ec;
    const int idx = blockIdx.x;
    const int b = idx >> 8, n = idx & 255;
    const int t = threadIdx.x;
    if (t == 0) ec = 0;
    __syncthreads();
#pragma unroll
    for (int e0 = 0; e0 < 2; e0++) {
        int row = b * 512 + t + e0 * 256;
        int s = edges[row * 3 + 0] & 255;
        int o = edges[row * 3 + 2] & 255;
        if (s == n) { int ps = atomicAdd(&ec, 1); ent[ps] = row << 1; }
        if (o == n) { int po = atomicAdd(&ec, 1); ent[po] = (row << 1) | 1; }
    }
    __syncthreads();
    const int c = ec;
    float a0 = 0.f, a1 = 0.f;
    for (int j = 0; j < c; ++j) {
        int v = ent[j];
        const bf16x2* rp = (const bf16x2*)(((v & 1) ? new_o : new_s) +
                                           (unsigned)(v >> 1) * 512u);
        bf16x2 w = rp[t];
        a0 += (float)w[0];
        a1 += (float)w[1];
    }
    float inv = 1.f / (float)(c > 1 ? c : 1);
    bf16x2 o2 = { (bf16)(a0 * inv), (bf16)(a1 * inv) };
    *(bf16x2*)(out + (unsigned)idx * 512u + (unsigned)(t * 2)) = o2;
}

extern "C" void kernel_launch(void* const* d_in, const int* in_sizes, int n_in,
                              void* d_out, int out_size, void* d_ws, size_t ws_size,
                              hipStream_t stream) {
    const float* obj_f  = (const float*)d_in[0];
    const float* pred_f = (const float*)d_in[1];
    const int*   edges  = (const int*)d_in[2];
    const float* w1 = (const float*)d_in[3];
    const float* b1 = (const float*)d_in[4];
    const float* w2 = (const float*)d_in[5];
    const float* b2 = (const float*)d_in[6];
    const float* w3 = (const float*)d_in[7];
    const float* b3 = (const float*)d_in[8];
    const float* w4 = (const float*)d_in[9];
    const float* b4 = (const float*)d_in[10];

    // workspace layout — 88 MB
    char* ws = (char*)d_ws;
    bf16* obj_bf  = (bf16*)(ws + 0);            // 16 MB   [dead after gemm1]
    bf16* pred_bf = (bf16*)(ws + 16777216);     // 32 MB   [dead after gemm1]
    bf16* new_s   = (bf16*)(ws + 0);            // 32 MB   overlays obj/pred
    bf16* w1t = (bf16*)(ws + 50331648);         // 512 x 1536
    bf16* w2t = (bf16*)(ws + 51904512);         // 1536 x 512
    bf16* w3t = (bf16*)(ws + 53477376);         // 512 x 512
    bf16* w4t = (bf16*)(ws + 54001664);         // 512 x 512
    bf16* hid = (bf16*)(ws + 54525952);         // 32768 x 512 (32 MB) [dead after gemm2]
    bf16* pooled_bf = hid;                      // 16 MB, reuse after gemm2
    bf16* h2  = (bf16*)(ws + 71303168);         // 16 MB

    float* out_obj = (float*)d_out;             // 64*256*512 f32 (32 MiB)
    float* out_p   = (float*)d_out + 8388608;   // 64*512*512 f32
    bf16* new_o    = (bf16*)d_out;              // 32 MiB scratch in out_obj region;
                                                // overwritten by gemm4 at the end

    // cvt obj/pred to bf16 + weight transposes (fused)
    pre_k<<<26624, 256, 0, stream>>>((const float4*)obj_f, (const float4*)pred_f,
                                     (bf16x4*)obj_bf, (bf16x4*)pred_bf,
                                     w1, w1t, w2, w2t, w3, w3t, w4, w4t);

    // gemm1: gathered [obj[s]|pred|obj[o]] (K=1536) -> hid
    gemm_k<0, 4><<<1024, 256, 0, stream>>>(
        nullptr, w1t, b1, hid, nullptr, nullptr, edges, obj_bf, pred_bf, 1536);

    // gemm2: hid @ w2t -> new_s | out_p | new_o
    gemm_k<1, 12><<<3072, 256, 0, stream>>>(
        hid, w2t, b2, new_s, out_p, new_o, nullptr, nullptr, nullptr, 512);

    // self-contained scatter-mean pool
    pool3_k<<<16384, 256, 0, stream>>>(edges, new_s, new_o, pooled_bf);

    // gemm3: pooled @ w3t -> h2
    gemm_k<2, 4><<<512, 256, 0, stream>>>(
        pooled_bf, w3t, b3, h2, nullptr, nullptr, nullptr, nullptr, nullptr, 512);

    // gemm4: h2 @ w4t -> out_obj (f32)
    gemm_k<3, 4><<<512, 256, 0, stream>>>(
        h2, w4t, b4, nullptr, out_obj, nullptr, nullptr, nullptr, nullptr, 512);
}